// Round 12
// baseline (293.718 us; speedup 1.0000x reference)
//
#include <hip/hip_runtime.h>
#include <cstdint>

// Problem constants (from reference)
#define BB 32
#define TV 8192
#define KK 64
#define TS 128
#define MARGIN_F 0.1f
#define LAMBDA_F 0.5f

typedef unsigned long long u64;
typedef unsigned int u32;

static constexpr int KB_PAIRS = KK * BB;       // 2048 (k,b) rows
static constexpr int W32_PER_B = TV / 32;      // 256 u32 mask words per batch
static constexpr int W64_PER_B = TV / 64;      // 128 u64 mask words per batch

// Workspace layout (u32 units from base):
//   gsa[2048] f32 | gsv[2048] f32 | gca[2048] f32 | len[32] i32 | mw[32] i32
//   vbit[32*256] u32 (32 KB) | pl[32*128*128] u64 (4 MB)
// pl u64 word for (b, g64, s): pl64[b*16384 + g64*128 + s]; u32 half h=g2&1.
//
// R15: STREAMING double-buffered packer (T3/T4 counted-vmcnt pattern).
// History: every packer so far was one-shot per block (stage, vmcnt(0)
// drain, transpose, exit) -> cold-start latency per block + serialized
// stage->consume: ballot 119us, LDS-DMA 75us, reg/asm-gather 95us, 1-wave
// DMA ~65-75us (R14, bounded via bench totals). R15: each 1-wave block owns
// 4 consecutive groups with 2x16KB LDS bufs: DMA(j+1,buf^1) | transpose(j)
// | s_waitcnt vmcnt(2) (NOT 0: the 2 newest are our stores, the 16 DMAs
// stay in flight under the ~600cy transpose). global_load_lds has no reg
// consumer -> hipcc cannot sink it (the R5/R6/R12/R13 pathology is
// structurally impossible). Masks hoisted (2 coalesced mv loads + 2
// ballots). Invalid groups: skip DMA, store zero planes. reduce/fin/layout
// byte-identical to R14 (passed). Prediction: packer ~20-30us, bench
// 282 -> 225-245. Pre-committed: bench >= 270 => gt-pack wall is real;
// revert to R8 monolith (best 259.4) and micro-tune its epilogue.

// ---------------------------------------------------------------------------
__device__ __forceinline__ void dma16(const int* __restrict__ gsrc_i,
                                      int* ldst_i, int lane) {
  const char* gsrc = (const char*)gsrc_i;
  char* ldst = (char*)ldst_i;
#pragma unroll
  for (int i = 0; i < 16; ++i) {
    __builtin_amdgcn_global_load_lds(
        (const __attribute__((address_space(1))) u32*)(gsrc + i * 1024 +
                                                       lane * 16),
        (__attribute__((address_space(3))) u32*)(ldst + i * 1024), 16, 0, 0);
  }
}

// transpose one 32-row x 128-col tile from LDS -> two plane words per lane.
// Exactly 2 global stores per lane on BOTH paths (vmcnt(2) bookkeeping).
__device__ __forceinline__ void trs(const int* bufp, u32 Vm,
                                    u32* __restrict__ outp, int lane) {
  if (Vm == 0u) {
    outp[2 * lane] = 0u;
    outp[2 * (lane + 64)] = 0u;
    return;
  }
#pragma unroll
  for (int p = 0; p < 2; ++p) {
    const int s = lane + 64 * p;                // bank = s%32 -> 2-way = free
    u32 wb = 0;
#pragma unroll
    for (int r = 0; r < 32; ++r)
      if (bufp[r * TS + s] > 0) wb |= 1u << r;
    outp[2 * s] = wb & Vm;                      // aligned requires valid
  }
}

#define WAITC(N)                                         \
  asm volatile("s_waitcnt vmcnt(" #N ")" ::: "memory"); \
  __builtin_amdgcn_sched_barrier(0)

// ---------------------------------------------------------------------------
// K2 v6: streaming packer. Block = 1 wave, 4 consecutive 32-row groups.
// group g in [0,8192): b = g>>8, g2 = g&255, rows [g*32, g*32+32).
// ---------------------------------------------------------------------------
__global__ __launch_bounds__(64) void plane_kernel(
    const int* __restrict__ gt, const int* __restrict__ mv,
    u32* __restrict__ vbit, u32* __restrict__ pl,
    int* __restrict__ len, int* __restrict__ mw) {
  const int lane = threadIdx.x;
  const int wid = blockIdx.x;                  // 0..2047
  __shared__ __align__(16) int buf0[32 * TS];  // 16 KB
  __shared__ __align__(16) int buf1[32 * TS];  // 16 KB

  const int g0 = wid * 4;                      // 4 consecutive groups
  const int rbase = g0 * 32;                   // first global row (= mv index)

  // hoisted validity: 2 coalesced loads cover all 128 rows; 2 ballots
  const int m0 = mv[rbase + lane];
  const int m1 = mv[rbase + 64 + lane];
  const u64 B0 = __ballot(m0 != 0);
  const u64 B1 = __ballot(m1 != 0);
  u32 V[4];
  V[0] = (u32)B0;
  V[1] = (u32)(B0 >> 32);
  V[2] = (u32)B1;
  V[3] = (u32)(B1 >> 32);

  if (lane == 0) {
#pragma unroll
    for (int j = 0; j < 4; ++j) {
      const int g = g0 + j, b = g >> 8, g2 = g & 255;
      vbit[b * W32_PER_B + g2] = V[j];         // always (ws poisoned)
      if (V[j]) {
        atomicAdd(&len[b], __popc(V[j]));
        atomicMax(&mw[b], g2);
      }
    }
  }

  u32* outp[4];
#pragma unroll
  for (int j = 0; j < 4; ++j) {
    const int g = g0 + j, b = g >> 8, g2 = g & 255;
    outp[j] = pl + ((size_t)(b * 128 + (g2 >> 1)) * TS) * 2 + (g2 & 1);
  }

  const int* gbase = gt + (size_t)rbase * TS;  // group j at + j*32*TS

  // ---- software pipeline: DMA(j+1) || transpose(j), counted vmcnt ----
  if (V[0]) dma16(gbase, buf0, lane);
  WAITC(0);                                    // prologue: buf0 ready

  if (V[1]) dma16(gbase + 1 * 32 * TS, buf1, lane);
  trs(buf0, V[0], outp[0], lane);
  WAITC(2);                                    // 16 DMAs done; 2 stores fly

  if (V[2]) dma16(gbase + 2 * 32 * TS, buf0, lane);
  trs(buf1, V[1], outp[1], lane);
  WAITC(2);

  if (V[3]) dma16(gbase + 3 * 32 * TS, buf1, lane);
  trs(buf0, V[2], outp[2], lane);
  WAITC(2);

  trs(buf1, V[3], outp[3], lane);
}

// ---------------------------------------------------------------------------
// K3: one block per (k,b) row of pi. Direct stores, no global atomics.
// (byte-identical to R14 — passed)
// ---------------------------------------------------------------------------
__global__ __launch_bounds__(256, 4) void reduce_kernel(
    const float* __restrict__ po, const float* __restrict__ pi,
    const int* __restrict__ idx,
    const u32* __restrict__ vbit, const u32* __restrict__ pl,
    const int* __restrict__ mw,
    float* __restrict__ gsa, float* __restrict__ gsv,
    float* __restrict__ gca) {
  const int tid = threadIdx.x;
  const int lane = tid & 63;
  const int w = tid >> 6;
  const int kb = blockIdx.x;                   // k*BB + b
  const int b = kb & (BB - 1);
  const int k = kb >> 5;
  const int c = idx[k];                        // this k's sentence column
  const u64* plb = (const u64*)pl + (size_t)b * (128 * TS) + c;
  const u64* vrow = (const u64*)vbit + (size_t)b * W64_PER_B;
  const float* pirow = pi + (size_t)kb * TV;
  const float* porow = po + (size_t)b * TV;

  __shared__ float rs[4][2];
  __shared__ int rca;
  if (tid == 0) rca = 0;
  __syncthreads();

  // chunks of 1024 floats; clip by highest valid word (mw in u32-word units)
  const int nch = min(8, (mw[b] + 32) >> 5);
  const int sh = (tid & 15) * 4;               // nibble of this thread's 4 t's
  float sa = 0.f, sv = 0.f;
#pragma unroll 2
  for (int cc = 0; cc < nch; ++cc) {
    const int t = cc * 1024 + tid * 4;
    const int widx = t >> 6;                   // u64 word (= g64)
    const u64 vw = vrow[widx];                 // 16 lanes share -> L1 broadcast
    const u32 vb4 = (u32)((vw >> sh) & 15ull);
    if (vb4) {                                 // aligned subset of valid
      const u64 aw = plb[(size_t)widx * TS] & vw;
      const u32 ab4 = (u32)((aw >> sh) & 15ull);
      const float4 x = *(const float4*)(pirow + t);
      const float4 p = *(const float4*)(porow + t);   // po: L2-resident (1MB)
      const float e0 =
          fabsf(__fdividef(1.f, 1.f + __expf(-p.x)) -
                __fdividef(1.f, 1.f + __expf(-x.x)));
      const float e1 =
          fabsf(__fdividef(1.f, 1.f + __expf(-p.y)) -
                __fdividef(1.f, 1.f + __expf(-x.y)));
      const float e2 =
          fabsf(__fdividef(1.f, 1.f + __expf(-p.z)) -
                __fdividef(1.f, 1.f + __expf(-x.z)));
      const float e3 =
          fabsf(__fdividef(1.f, 1.f + __expf(-p.w)) -
                __fdividef(1.f, 1.f + __expf(-x.w)));
      if (vb4 & 1u) sv += e0;
      if (vb4 & 2u) sv += e1;
      if (vb4 & 4u) sv += e2;
      if (vb4 & 8u) sv += e3;
      if (ab4 & 1u) sa += e0;
      if (ab4 & 2u) sa += e1;
      if (ab4 & 4u) sa += e2;
      if (ab4 & 8u) sa += e3;
    }
  }
  // 64-lane butterfly, then 4-wave combine
#pragma unroll
  for (int off = 32; off; off >>= 1) {
    sa += __shfl_xor(sa, off);
    sv += __shfl_xor(sv, off);
  }
  if (lane == 0) {
    rs[w][0] = sa;
    rs[w][1] = sv;
  }
  if (tid < W64_PER_B)
    atomicAdd(&rca, __popcll(plb[(size_t)tid * TS] & vrow[tid]));  // LDS atomic
  __syncthreads();
  if (tid == 0) {
    gsa[kb] = rs[0][0] + rs[1][0] + rs[2][0] + rs[3][0];
    gsv[kb] = rs[0][1] + rs[1][1] + rs[2][1] + rs[3][1];
    gca[kb] = (float)rca;
  }
}

// ---------------------------------------------------------------------------
// Finalize: 1 block over the 2048 (k,b) pairs (logic verified in R2/R3).
// ---------------------------------------------------------------------------
__global__ __launch_bounds__(256) void fin_kernel(
    const float* __restrict__ gsa, const float* __restrict__ gsv,
    const float* __restrict__ gca, const int* __restrict__ len,
    float* __restrict__ out) {
  float s = 0.f;
  for (int i = threadIdx.x; i < KB_PAIRS; i += 256) {
    const int b = i & (BB - 1);
    const float ca = gca[i];
    const float cn = (float)len[b] - ca;
    if (ca > 0.f && cn > 0.f) {
      const float sa = gsa[i];
      const float sv = gsv[i];
      const float d = MARGIN_F - (sa / ca - (sv - sa) / cn);
      s += d > 0.f ? d : 0.f;
    }
  }
#pragma unroll
  for (int off = 32; off > 0; off >>= 1) s += __shfl_down(s, off);
  __shared__ float ws4[4];
  if ((threadIdx.x & 63) == 0) ws4[threadIdx.x >> 6] = s;
  __syncthreads();
  if (threadIdx.x == 0) {
    const float S = ws4[0] + ws4[1] + ws4[2] + ws4[3];
    const float ac = S * (1.0f / (float)KB_PAIRS);
    out[0] = ac;
    out[1] = ac * LAMBDA_F;
  }
}

extern "C" void kernel_launch(void* const* d_in, const int* in_sizes, int n_in,
                              void* d_out, int out_size, void* d_ws, size_t ws_size,
                              hipStream_t stream) {
  const float* pred_orig = (const float*)d_in[0];   // [B,TV] fp32
  const float* pred_int  = (const float*)d_in[1];   // [K,B,TV] fp32
  const int*   idx       = (const int*)d_in[2];     // [K] int32
  const int*   gt        = (const int*)d_in[3];     // [B,TV,TS] int32
  const int*   mv        = (const int*)d_in[4];     // [B,TV] int32
  float* out = (float*)d_out;

  float* gsa = (float*)d_ws;                        // [2048]
  float* gsv = gsa + KB_PAIRS;                      // [2048]
  float* gca = gsv + KB_PAIRS;                      // [2048]
  int*   len = (int*)(gca + KB_PAIRS);              // [32]
  int*   mw  = len + BB;                            // [32]
  u32*   vbit = (u32*)(mw + BB);                    // [32*256]  32 KB
  u32*   pl   = vbit + BB * W32_PER_B;              // [32*128*128] u64 = 4 MB

  // only len+mw need zeroing (256 B); everything else is written before read
  hipMemsetAsync(len, 0, 2 * BB * sizeof(int), stream);
  plane_kernel<<<2048, 64, 0, stream>>>(gt, mv, vbit, pl, len, mw);
  reduce_kernel<<<KB_PAIRS, 256, 0, stream>>>(pred_orig, pred_int, idx, vbit,
                                              pl, mw, gsa, gsv, gca);
  fin_kernel<<<1, 256, 0, stream>>>(gsa, gsv, gca, len, out);
}

// Round 13
// 259.963 us; speedup vs baseline: 1.1298x; 1.1298x over previous
//
#include <hip/hip_runtime.h>
#include <cstdint>

// Problem constants (from reference)
#define BB 32
#define TV 8192
#define KK 64
#define TS 128
#define MARGIN_F 0.1f
#define LAMBDA_F 0.5f

#define TT 256                                 // t-tile per block
static constexpr int KSTR = BB * TV;           // pred_intervened stride per k
static constexpr int NTILE = TV / TT;          // 32 tiles per batch

// R16: R8 monolith (best measured: 83us fused / 259.4 bench) with ONE
// change: slab halved ([64][65] -> [32][65] reused across two k-halves),
// LDS 36.9KB -> ~20KB -> 8 blocks/CU = 32 waves/CU (R8 ran 16; R7's
// "32-wave" test was confounded: 512-thr at 2 blocks/CU is still 16).
// Ledger justifying the revert: 7 structures (ballot 119us, LDS-DMA 75,
// reg/asm gather 95/95, 1-wave DMA ~70, pipelined DMA 83, monolith 83)
// all land 75-95us on gt regardless of MLP/TLP/phase structure, while the
// monolith gets the whole pi-reduction for free in the same 83 -> fusion
// wins; only untested monolith lever is occupancy. Cost: 3 extra barriers.
// Pre-committed: fused flat ~80-85 despite 2x residency => ambient wall
// (plausibly the 536MB ws-poison writeback storm preceding us) => revert
// to R8-exact and declare the structural floor.
__global__ __launch_bounds__(256, 8) void fused_kernel(
    const float* __restrict__ po, const float* __restrict__ pi,
    const int* __restrict__ idx, const int* __restrict__ gt,
    const int* __restrict__ mv,
    float* __restrict__ gsa, float* __restrict__ gsv,
    float* __restrict__ gca, int* __restrict__ len) {
  const int tid = threadIdx.x;
  const int lane = tid & 63;
  const int w = tid >> 6;
  const int bid = blockIdx.x;
  const int b = bid >> 5;                      // log2(NTILE)=5
  const int tile = ((bid & 31) + b) & 31;      // R8 rotation (+5%, proven)
  const int t0 = tile * TT;

  __shared__ unsigned long long planes[4][65]; // [group][k], +1 pad
  __shared__ unsigned long long sVg[4];        // valid bits per group
  __shared__ float so[TT];                     // sigmoid(pred_orig) tile
  __shared__ float saL[32][65];                // HALF-slab (k-halves reuse)
  __shared__ float svL[32][65];

  // ---- Phase A (byte-identical to R8) ----
  const int r0 = b * TV + t0 + w * 64;
  const unsigned long long V = __ballot(mv[r0 + lane] != 0);
  if (lane == 0) {
    sVg[w] = V;
    if (V) atomicAdd(&len[b], __popcll(V));
  }
  so[tid] = __fdividef(1.f, 1.f + __expf(-po[b * TV + t0 + tid]));

  const int c = idx[lane];
  const int csel = c & 3, csh = c >> 2;
  unsigned long long plane = 0ull;
  if (V != 0ull) {
    const int4* rowp = (const int4*)(gt + (size_t)r0 * TS);
#pragma unroll 4
    for (int ch = 0; ch < 32; ++ch) {
      int4 v = rowp[ch * 64 + lane];
      unsigned long long b0 = __ballot(v.x > 0);
      unsigned long long b1 = __ballot(v.y > 0);
      unsigned long long b2 = __ballot(v.z > 0);
      unsigned long long b3 = __ballot(v.w > 0);
      unsigned long long sel =
          (csel == 0) ? b0 : (csel == 1) ? b1 : (csel == 2) ? b2 : b3;
      const unsigned long long raw0 = (sel >> csh) & 1ull;
      const unsigned long long raw1 = (sel >> (32 + csh)) & 1ull;
      plane |= (raw0 << (2 * ch)) | (raw1 << (2 * ch + 1));
    }
    plane &= V;
  }
  planes[w][lane] = plane;
  __syncthreads();

  if ((sVg[0] | sVg[1] | sVg[2] | sVg[3]) == 0ull) return;

  // ---- Phase B common per-lane state (identical to R8) ----
  const int g = lane >> 4;
  const int sh4 = (lane & 15) * 4;
  const unsigned vb4 = (unsigned)((sVg[g] >> sh4) & 15ull);
  const float4 so4 = *(const float4*)&so[lane * 4];
  const float* pib = pi + (size_t)b * TV + t0 + lane * 4;

#pragma unroll
  for (int half = 0; half < 2; ++half) {
    // ---- Phase B half: wave w handles k = w*16 + half*8 + kk, kk<8 ----
#pragma unroll 4
    for (int kk = 0; kk < 8; ++kk) {
      const int k = w * 16 + half * 8 + kk;
      const float4 xi = *(const float4*)(pib + (size_t)k * KSTR);
      const unsigned ab4 = (unsigned)((planes[g][k] >> sh4) & 15ull);
      float sa = 0.f, sv = 0.f;
      {
        const float e = fabsf(so4.x - __fdividef(1.f, 1.f + __expf(-xi.x)));
        if (ab4 & 1u) sa += e;
        if (vb4 & 1u) sv += e;
      }
      {
        const float e = fabsf(so4.y - __fdividef(1.f, 1.f + __expf(-xi.y)));
        if (ab4 & 2u) sa += e;
        if (vb4 & 2u) sv += e;
      }
      {
        const float e = fabsf(so4.z - __fdividef(1.f, 1.f + __expf(-xi.z)));
        if (ab4 & 4u) sa += e;
        if (vb4 & 4u) sv += e;
      }
      {
        const float e = fabsf(so4.w - __fdividef(1.f, 1.f + __expf(-xi.w)));
        if (ab4 & 8u) sa += e;
        if (vb4 & 8u) sv += e;
      }
      saL[w * 8 + kk][lane] = sa;              // wave-exclusive slab rows
      svL[w * 8 + kk][lane] = sv;
    }
    __syncthreads();

    // ---- epilogue half: 32 slab rows -> k = (sr>>3)*16 + half*8 + (sr&7)
    if (tid < 32) {
      const int sr = tid;
      const int k = (sr >> 3) * 16 + half * 8 + (sr & 7);
      float S = 0.f;
#pragma unroll 8
      for (int j = 0; j < 64; ++j) S += saL[sr][j];
      atomicAdd(&gsa[k * BB + b], S);
    } else if (tid >= 64 && tid < 96) {
      const int sr = tid - 64;
      const int k = (sr >> 3) * 16 + half * 8 + (sr & 7);
      float S = 0.f;
#pragma unroll 8
      for (int j = 0; j < 64; ++j) S += svL[sr][j];
      atomicAdd(&gsv[k * BB + b], S);
    } else if (half == 1 && tid >= 128 && tid < 192) {
      const int k = tid - 128;                 // ca once, from planes
      int ca = 0;
#pragma unroll
      for (int gg = 0; gg < 4; ++gg) ca += __popcll(planes[gg][k]);
      if (ca) atomicAdd(&gca[k * BB + b], (float)ca);
    }
    if (half == 0) __syncthreads();            // slab reuse safety
  }
}

// ---------------------------------------------------------------------------
// Finalize: 1 block over the 2048 (k,b) pairs (logic verified in R2/R3).
// ---------------------------------------------------------------------------
__global__ __launch_bounds__(256) void fin_kernel(
    const float* __restrict__ gsa, const float* __restrict__ gsv,
    const float* __restrict__ gca, const int* __restrict__ len,
    float* __restrict__ out) {
  float s = 0.f;
  for (int i = threadIdx.x; i < KK * BB; i += 256) {
    const int b = i & (BB - 1);
    const float ca = gca[i];
    const float cn = (float)len[b] - ca;
    if (ca > 0.f && cn > 0.f) {
      const float sa = gsa[i];
      const float sv = gsv[i];
      const float d = MARGIN_F - (sa / ca - (sv - sa) / cn);
      s += d > 0.f ? d : 0.f;
    }
  }
#pragma unroll
  for (int off = 32; off > 0; off >>= 1) s += __shfl_down(s, off);
  __shared__ float ws4[4];
  if ((threadIdx.x & 63) == 0) ws4[threadIdx.x >> 6] = s;
  __syncthreads();
  if (threadIdx.x == 0) {
    const float S = ws4[0] + ws4[1] + ws4[2] + ws4[3];
    const float ac = S * (1.0f / (float)(KK * BB));
    out[0] = ac;
    out[1] = ac * LAMBDA_F;
  }
}

extern "C" void kernel_launch(void* const* d_in, const int* in_sizes, int n_in,
                              void* d_out, int out_size, void* d_ws, size_t ws_size,
                              hipStream_t stream) {
  const float* pred_orig = (const float*)d_in[0];   // [B,TV] fp32
  const float* pred_int  = (const float*)d_in[1];   // [K,B,TV] fp32
  const int*   idx       = (const int*)d_in[2];     // [K] int32
  const int*   gt        = (const int*)d_in[3];     // [B,TV,TS] int32
  const int*   mv        = (const int*)d_in[4];     // [B,TV] int32
  float* out = (float*)d_out;

  float* gsa = (float*)d_ws;
  float* gsv = gsa + KK * BB;
  float* gca = gsv + KK * BB;
  int*   len = (int*)(gca + KK * BB);

  // zero the 24.7 KB accumulator region (ws re-poisoned to 0xAA each call)
  hipMemsetAsync(d_ws, 0, (size_t)(3 * KK * BB) * sizeof(float) + BB * sizeof(int),
                 stream);
  fused_kernel<<<BB * NTILE, 256, 0, stream>>>(
      pred_orig, pred_int, idx, gt, mv, gsa, gsv, gca, len);
  fin_kernel<<<1, 256, 0, stream>>>(gsa, gsv, gca, len, out);
}